// Round 3
// baseline (757.684 us; speedup 1.0000x reference)
//
#include <hip/hip_runtime.h>

#define B_ 16
#define N_ 2048
#define M_ 2048
#define ROWS 32    // rows per block (band)
#define WROWS 8    // rows per wave (4 waves/block)
#define KCAP 4     // sparse-capture capacity per row (overflow -> dense fallback)

__device__ __forceinline__ float wave_sum(float v) {
#pragma unroll
    for (int off = 32; off >= 1; off >>= 1) v += __shfl_xor(v, off);
    return v;
}

// K1: stream gt ONLY; capture nonzero (col,val) per valid row. No pred read.
extern "C" __global__ __launch_bounds__(256) void k_gt(
    const float* __restrict__ gt,
    const int* __restrict__ src_ns, const int* __restrict__ tgt_ns,
    int* __restrict__ nnz, int* __restrict__ ent_col,
    float* __restrict__ ent_val, int* flag)
{
    const int b = blockIdx.y;
    const int src = src_ns[b];
    const int band = blockIdx.x;
    if (band * ROWS >= src) return;
    const int tgt = tgt_ns[b];
    const int wave = threadIdx.x >> 6, lane = threadIdx.x & 63;
    const int base = b * (N_ * M_);
    const int jmax = (tgt + 255) >> 8;   // skip whole 256-col blocks past tgt

    const int row0 = band * ROWS + wave * WROWS;
    for (int r = 0; r < WROWS; ++r) {
        const int n = row0 + r;
        if (n >= src) break;          // rows ascending; wave-uniform
        const int ri = b * N_ + n;
        const float4* grow = (const float4*)(gt + base + n * M_);
        for (int j = 0; j < 8; ++j) {
            if (j >= jmax) break;
            const int m4 = j * 64 + lane;
            const float4 g4 = grow[m4];
            if (g4.x != 0.f || g4.y != 0.f || g4.z != 0.f || g4.w != 0.f) {
                const int mb = m4 * 4;
#define GC(KK, MB) do { \
    const int c = mb + KK; \
    const float gv = g4.MB; \
    if (gv != 0.f && c < tgt) { \
        const int slot = atomicAdd(&nnz[ri], 1); \
        if (slot < KCAP) { ent_col[ri * KCAP + slot] = c; ent_val[ri * KCAP + slot] = gv; } \
        else *flag = 1; \
    } \
} while (0)
                GC(0, x); GC(1, y); GC(2, z); GC(3, w);
#undef GC
            }
        }
    }
}

// K2 (tiny): build row_gt/row_cnt/col_gt/col_cnt from captured entries.
extern "C" __global__ __launch_bounds__(256) void k_mid(
    const float* __restrict__ pred,
    const int* __restrict__ src_ns,
    const int* __restrict__ nnz, const int* __restrict__ ent_col,
    const float* __restrict__ ent_val, const int* flag,
    float* __restrict__ row_gt, float* __restrict__ row_cnt,
    float* __restrict__ col_gt, float* __restrict__ col_cnt)
{
    if (*flag) return;   // dense fallback kernel will produce the stats
    const int ri = blockIdx.x * 256 + threadIdx.x;
    const int b = ri >> 11, n = ri & (N_ - 1);
    if (n >= src_ns[b]) { row_gt[ri] = 0.f; row_cnt[ri] = 0.f; return; }
    const int nn0 = nnz[ri];
    const int nn = nn0 < KCAP ? nn0 : KCAP;
    float rg = 0.f, rc = 0.f;
    for (int s = 0; s < nn; ++s) {
        const int c = ent_col[ri * KCAP + s];
        const float gv = ent_val[ri * KCAP + s];
        float p = pred[b * (N_ * M_) + n * M_ + c];
        p = fminf(fmaxf(p, 0.f), 1.f);
        rg += gv * p; rc += gv;
        atomicAdd(&col_gt[b * M_ + c], gv * p);
        atomicAdd(&col_cnt[b * M_ + c], gv);
    }
    row_gt[ri] = rg; row_cnt[ri] = rc;
}

// Dense fallback pass1 (runs only if capture overflowed): original round-0 pass1.
extern "C" __global__ __launch_bounds__(256) void k_p1d(
    const float* __restrict__ pred, const float* __restrict__ gt,
    const int* __restrict__ src_ns, const int* __restrict__ tgt_ns,
    const int* flag,
    float* __restrict__ row_gt, float* __restrict__ row_cnt,
    float* __restrict__ col_gt, float* __restrict__ col_cnt)
{
    if (*flag == 0) return;
    const int b = blockIdx.y;
    const int src = src_ns[b];
    const int band = blockIdx.x;
    if (band * ROWS >= src) return;
    const int tgt = tgt_ns[b];
    const int wave = threadIdx.x >> 6, lane = threadIdx.x & 63;
    const int base = b * (N_ * M_);

    float4 acg[8], accn[8];
#pragma unroll
    for (int j = 0; j < 8; ++j) { acg[j] = make_float4(0,0,0,0); accn[j] = make_float4(0,0,0,0); }

    const int row0 = band * ROWS + wave * WROWS;
    for (int r = 0; r < WROWS; ++r) {
        const int n = row0 + r;
        if (n >= src) break;
        const float4* prow = (const float4*)(pred + base + n * M_);
        const float4* grow = (const float4*)(gt + base + n * M_);
        float rg = 0.f, rc = 0.f;
#pragma unroll
        for (int j = 0; j < 8; ++j) {
            const int m4 = j * 64 + lane;
            const float4 p4 = prow[m4];
            const float4 g4 = grow[m4];
            const int mb = m4 * 4;
#define P1C(KK, MB) do { \
    const bool ok = (mb + KK) < tgt; \
    float p = fminf(fmaxf(p4.MB, 0.f), 1.f); p = ok ? p : 0.f; \
    const float g = ok ? g4.MB : 0.f; \
    const float gp = p * g; \
    rg += gp; rc += g; \
    acg[j].MB += gp; accn[j].MB += g; \
} while (0)
            P1C(0, x); P1C(1, y); P1C(2, z); P1C(3, w);
#undef P1C
        }
        rg = wave_sum(rg); rc = wave_sum(rc);
        if (lane == 0) { row_gt[b * N_ + n] = rg; row_cnt[b * N_ + n] = rc; }
    }

    __shared__ float4 s_cg[M_ / 4];
    __shared__ float4 s_cc[M_ / 4];
    for (int i = threadIdx.x; i < M_ / 4; i += 256) {
        s_cg[i] = make_float4(0,0,0,0);
        s_cc[i] = make_float4(0,0,0,0);
    }
    __syncthreads();
    for (int w = 0; w < 4; ++w) {
        if (wave == w) {
#pragma unroll
            for (int j = 0; j < 8; ++j) {
                const int i = j * 64 + lane;
                float4 v = s_cg[i];
                v.x += acg[j].x; v.y += acg[j].y; v.z += acg[j].z; v.w += acg[j].w;
                s_cg[i] = v;
                float4 u = s_cc[i];
                u.x += accn[j].x; u.y += accn[j].y; u.z += accn[j].z; u.w += accn[j].w;
                s_cc[i] = u;
            }
        }
        __syncthreads();
    }
    const float* fcg = (const float*)s_cg;
    const float* fcc = (const float*)s_cc;
    for (int i = threadIdx.x; i < M_; i += 256) {
        atomicAdd(&col_gt[b * M_ + i], fcg[i]);
        atomicAdd(&col_cnt[b * M_ + i], fcc[i]);
    }
}

// K3: stream pred ONLY (sparse path). rth known up-front -> single pass for
// src_neg/src_pos/tgt_neg, with exact sparse-g corrections. Dense fallback
// branch reads gt as well.
extern "C" __global__ __launch_bounds__(256) void k_pred(
    const float* __restrict__ pred, const float* __restrict__ gt,
    const int* __restrict__ src_ns, const int* __restrict__ tgt_ns,
    const float* __restrict__ beta_p,
    const float* __restrict__ row_gt, const float* __restrict__ row_cnt,
    const float* __restrict__ col_gt, const float* __restrict__ col_cnt,
    const int* __restrict__ nnz, const int* __restrict__ ent_col,
    const float* __restrict__ ent_val, const int* flag,
    float* __restrict__ src_neg, float* __restrict__ src_pos,
    float* __restrict__ tgt_neg)
{
    const int b = blockIdx.y;
    const int src = src_ns[b];
    const int band = blockIdx.x;
    if (band * ROWS >= src) return;
    const int tgt = tgt_ns[b];
    const float beta = beta_p[0];
    const int wave = threadIdx.x >> 6, lane = threadIdx.x & 63;
    const int base = b * (N_ * M_);
    const bool dense = (*flag != 0);
    const int jmax = (tgt + 255) >> 8;

    // cgb = col_gt - beta (threshold pre-subtracted), cc = col_cnt
    float4 cgb[8], cc[8], tn[8];
    const float4* cg4 = (const float4*)(col_gt + b * M_);
    const float4* cc4 = (const float4*)(col_cnt + b * M_);
#pragma unroll
    for (int j = 0; j < 8; ++j) {
        float4 v = cg4[j * 64 + lane];
        v.x -= beta; v.y -= beta; v.z -= beta; v.w -= beta;
        cgb[j] = v;
        cc[j] = cc4[j * 64 + lane];
        tn[j] = make_float4(0,0,0,0);
    }

    const int row0 = band * ROWS + wave * WROWS;
    if (!dense) {
        for (int r = 0; r < WROWS; ++r) {
            const int n = row0 + r;
            if (n >= src) break;
            const int ri = b * N_ + n;
            const float rc = row_cnt[ri];
            const float rth = row_gt[ri] - beta;
            const float4* prow = (const float4*)(pred + base + n * M_);
            float sneg = 0.f, spos = 0.f;
            for (int j = 0; j < 8; ++j) {
                if (j >= jmax) break;
                const int m4 = j * 64 + lane;
                const float4 p4 = prow[m4];
                const int mb = m4 * 4;
#define P2S(KK, MB) do { \
    const bool ok = (mb + KK) < tgt; \
    float p = fminf(fmaxf(p4.MB, 0.f), 1.f); p = ok ? p : 0.f; \
    const float as = (p >= rth) ? rc : 0.f; \
    const float ds = as * p; \
    sneg += ds * ds; \
    const float at = (p >= cgb[j].MB) ? cc[j].MB : 0.f; \
    const float d = at * p; \
    tn[j].MB += d * d; \
} while (0)
                P2S(0, x); P2S(1, y); P2S(2, z); P2S(3, w);
#undef P2S
            }
            sneg = wave_sum(sneg);
            // spos base is 0 (g==0 everywhere in base pass); corrections add it.
            if (lane == 0) {
                const int nn0 = nnz[ri];
                const int nn = nn0 < KCAP ? nn0 : KCAP;
                for (int s = 0; s < nn; ++s) {
                    const int c = ent_col[ri * KCAP + s];   // c < tgt by capture
                    const float gv = ent_val[ri * KCAP + s];
                    float pv = pred[base + n * M_ + c];
                    pv = fminf(fmaxf(pv, 0.f), 1.f);
                    // src corrections
                    const float as = (pv >= rth) ? rc : 0.f;
                    const float d0 = as * pv;
                    const float d1 = (as - gv) * pv;
                    sneg += d1 * d1 - d0 * d0;
                    const float gp = gv * pv;
                    spos += gp * gp;
                    // tgt correction
                    const float at = (pv >= col_gt[b * M_ + c] - beta) ? col_cnt[b * M_ + c] : 0.f;
                    const float t0 = at * pv;
                    const float t1 = (at - gv) * pv;
                    atomicAdd(&tgt_neg[b * M_ + c], t1 * t1 - t0 * t0);
                }
                src_neg[ri] = sneg; src_pos[ri] = spos;
            }
        }
    } else {
        for (int r = 0; r < WROWS; ++r) {
            const int n = row0 + r;
            if (n >= src) break;
            const int ri = b * N_ + n;
            const float rc = row_cnt[ri];
            const float rth = row_gt[ri] - beta;
            const float4* prow = (const float4*)(pred + base + n * M_);
            const float4* grow = (const float4*)(gt + base + n * M_);
            float sneg = 0.f, spos = 0.f;
#pragma unroll
            for (int j = 0; j < 8; ++j) {
                const int m4 = j * 64 + lane;
                const float4 p4 = prow[m4];
                const float4 g4 = grow[m4];
                const int mb = m4 * 4;
#define P2D(KK, MB) do { \
    const bool ok = (mb + KK) < tgt; \
    float p = fminf(fmaxf(p4.MB, 0.f), 1.f); p = ok ? p : 0.f; \
    const float gv = ok ? g4.MB : 0.f; \
    const float as = (p >= rth) ? rc : 0.f; \
    const float ds = (as - gv) * p; \
    sneg += ds * ds; \
    const float gp = gv * p; spos += gp * gp; \
    const float at = (p >= cgb[j].MB) ? cc[j].MB : 0.f; \
    const float dt = (at - gv) * p; \
    tn[j].MB += dt * dt; \
} while (0)
                P2D(0, x); P2D(1, y); P2D(2, z); P2D(3, w);
#undef P2D
            }
            sneg = wave_sum(sneg); spos = wave_sum(spos);
            if (lane == 0) { src_neg[ri] = sneg; src_pos[ri] = spos; }
        }
    }

    __shared__ float4 s_tn[M_ / 4];
    for (int i = threadIdx.x; i < M_ / 4; i += 256) s_tn[i] = make_float4(0,0,0,0);
    __syncthreads();
    for (int w = 0; w < 4; ++w) {
        if (wave == w) {
#pragma unroll
            for (int j = 0; j < 8; ++j) {
                const int i = j * 64 + lane;
                float4 v = s_tn[i];
                v.x += tn[j].x; v.y += tn[j].y; v.z += tn[j].z; v.w += tn[j].w;
                s_tn[i] = v;
            }
        }
        __syncthreads();
    }
    const float* ftn = (const float*)s_tn;
    for (int i = threadIdx.x; i < M_; i += 256)
        atomicAdd(&tgt_neg[b * M_ + i], ftn[i]);
}

// Final: corr[b] = dot(tgt_neg, col_cnt), then loss reduction -> single scalar
extern "C" __global__ __launch_bounds__(256) void k_final(
    const float* __restrict__ src_neg, const float* __restrict__ src_pos,
    const float* __restrict__ tgt_neg, const float* __restrict__ col_cnt,
    const int* __restrict__ src_ns, float* __restrict__ out)
{
    const int b = blockIdx.x;
    const int wave = threadIdx.x >> 6, lane = threadIdx.x & 63;
    __shared__ float sredc[4];
    __shared__ float sredl[4];

    float c = 0.f;
    for (int i = threadIdx.x; i < M_; i += 256)
        c += tgt_neg[b * M_ + i] * col_cnt[b * M_ + i];
    c = wave_sum(c);
    if (lane == 0) sredc[wave] = c;
    __syncthreads();
    const float corr = sredc[0] + sredc[1] + sredc[2] + sredc[3];

    const int src = src_ns[b];
    float ls = 0.f;
    for (int n = threadIdx.x; n < src; n += 256) {
        const float sp = src_pos[b * N_ + n];
        const float sn = src_neg[b * N_ + n];
        ls += logf(sp) - logf(1.f + sn + corr);
    }
    ls = wave_sum(ls);
    if (lane == 0) sredl[wave] = ls;
    __syncthreads();
    if (threadIdx.x == 0) {
        const float total = sredl[0] + sredl[1] + sredl[2] + sredl[3];
        float nsum = 0.f;
        for (int i = 0; i < B_; ++i) nsum += (float)src_ns[i];
        atomicAdd(out, -0.5f * total / nsum);
    }
}

extern "C" void kernel_launch(void* const* d_in, const int* in_sizes, int n_in,
                              void* d_out, int out_size, void* d_ws, size_t ws_size,
                              hipStream_t stream)
{
    const float* pred   = (const float*)d_in[0];
    const float* gtp    = (const float*)d_in[1];
    const int*   src_ns = (const int*)d_in[2];
    const int*   tgt_ns = (const int*)d_in[3];
    const float* beta   = (const float*)d_in[4];
    float* out = (float*)d_out;
    float* ws  = (float*)d_ws;

    // zeroed region first: [col_gt][col_cnt][tgt_neg][nnz][flag]
    float* col_gt  = ws;
    float* col_cnt = col_gt  + B_ * M_;
    float* tgt_neg = col_cnt + B_ * M_;
    int*   nnz     = (int*)(tgt_neg + B_ * M_);
    int*   flag    = nnz + B_ * N_;
    float* row_gt  = (float*)(flag + 1);
    float* row_cnt = row_gt  + B_ * N_;
    float* src_neg = row_cnt + B_ * N_;
    float* src_pos = src_neg + B_ * N_;
    int*   ent_col = (int*)(src_pos + B_ * N_);
    float* ent_val = (float*)(ent_col + B_ * N_ * KCAP);

    const size_t zero_bytes = (size_t)(3 * B_ * M_ + B_ * N_ + 1) * sizeof(float);
    hipMemsetAsync(d_ws, 0, zero_bytes, stream);
    hipMemsetAsync(d_out, 0, sizeof(float), stream);

    dim3 grid(N_ / ROWS, B_);
    k_gt<<<grid, 256, 0, stream>>>(gtp, src_ns, tgt_ns, nnz, ent_col, ent_val, flag);
    k_mid<<<(B_ * N_) / 256, 256, 0, stream>>>(pred, src_ns, nnz, ent_col, ent_val, flag,
                                               row_gt, row_cnt, col_gt, col_cnt);
    k_p1d<<<grid, 256, 0, stream>>>(pred, gtp, src_ns, tgt_ns, flag,
                                    row_gt, row_cnt, col_gt, col_cnt);
    k_pred<<<grid, 256, 0, stream>>>(pred, gtp, src_ns, tgt_ns, beta,
                                     row_gt, row_cnt, col_gt, col_cnt,
                                     nnz, ent_col, ent_val, flag,
                                     src_neg, src_pos, tgt_neg);
    k_final<<<B_, 256, 0, stream>>>(src_neg, src_pos, tgt_neg, col_cnt, src_ns, out);
}

// Round 4
// 581.154 us; speedup vs baseline: 1.3038x; 1.3038x over previous
//
#include <hip/hip_runtime.h>

#define B_ 16
#define N_ 2048
#define M_ 2048
#define ROWS 32    // rows per block (band)
#define WROWS 8    // rows per wave (4 waves/block)
#define KCAP 4     // sparse-capture capacity per row (overflow -> dense fallback)

__device__ __forceinline__ float wave_sum(float v) {
#pragma unroll
    for (int off = 32; off >= 1; off >>= 1) v += __shfl_xor(v, off);
    return v;
}

// K1: stream gt ONLY; capture nonzero (col,val) per valid row. No pred read.
extern "C" __global__ __launch_bounds__(256) void k_gt(
    const float* __restrict__ gt,
    const int* __restrict__ src_ns, const int* __restrict__ tgt_ns,
    int* __restrict__ nnz, int* __restrict__ ent_col,
    float* __restrict__ ent_val, int* flag)
{
    const int b = blockIdx.y;
    const int src = src_ns[b];
    const int band = blockIdx.x;
    if (band * ROWS >= src) return;
    const int tgt = tgt_ns[b];
    const int wave = threadIdx.x >> 6, lane = threadIdx.x & 63;
    const int base = b * (N_ * M_);
    const int jmax = (tgt + 255) >> 8;   // skip whole 256-col blocks past tgt

    const int row0 = band * ROWS + wave * WROWS;
    for (int r = 0; r < WROWS; ++r) {
        const int n = row0 + r;
        if (n >= src) break;          // rows ascending; wave-uniform
        const int ri = b * N_ + n;
        const float4* grow = (const float4*)(gt + base + n * M_);
        for (int j = 0; j < jmax; ++j) {   // no register arrays indexed by j: safe dynamic bound
            const int m4 = j * 64 + lane;
            const float4 g4 = grow[m4];
            if (g4.x != 0.f || g4.y != 0.f || g4.z != 0.f || g4.w != 0.f) {
                const int mb = m4 * 4;
#define GC(KK, MB) do { \
    const int c = mb + KK; \
    const float gv = g4.MB; \
    if (gv != 0.f && c < tgt) { \
        const int slot = atomicAdd(&nnz[ri], 1); \
        if (slot < KCAP) { ent_col[ri * KCAP + slot] = c; ent_val[ri * KCAP + slot] = gv; } \
        else *flag = 1; \
    } \
} while (0)
                GC(0, x); GC(1, y); GC(2, z); GC(3, w);
#undef GC
            }
        }
    }
}

// K2 (tiny): build row_gt/row_cnt/col_gt/col_cnt from captured entries.
extern "C" __global__ __launch_bounds__(256) void k_mid(
    const float* __restrict__ pred,
    const int* __restrict__ src_ns,
    const int* __restrict__ nnz, const int* __restrict__ ent_col,
    const float* __restrict__ ent_val, const int* flag,
    float* __restrict__ row_gt, float* __restrict__ row_cnt,
    float* __restrict__ col_gt, float* __restrict__ col_cnt)
{
    if (*flag) return;   // dense fallback kernel will produce the stats
    const int ri = blockIdx.x * 256 + threadIdx.x;
    const int b = ri >> 11, n = ri & (N_ - 1);
    if (n >= src_ns[b]) { row_gt[ri] = 0.f; row_cnt[ri] = 0.f; return; }
    const int nn0 = nnz[ri];
    const int nn = nn0 < KCAP ? nn0 : KCAP;
    float rg = 0.f, rc = 0.f;
    for (int s = 0; s < nn; ++s) {
        const int c = ent_col[ri * KCAP + s];
        const float gv = ent_val[ri * KCAP + s];
        float p = pred[b * (N_ * M_) + n * M_ + c];
        p = fminf(fmaxf(p, 0.f), 1.f);
        rg += gv * p; rc += gv;
        atomicAdd(&col_gt[b * M_ + c], gv * p);
        atomicAdd(&col_cnt[b * M_ + c], gv);
    }
    row_gt[ri] = rg; row_cnt[ri] = rc;
}

// Dense fallback pass1 (runs only if capture overflowed): original round-0 pass1.
extern "C" __global__ __launch_bounds__(256) void k_p1d(
    const float* __restrict__ pred, const float* __restrict__ gt,
    const int* __restrict__ src_ns, const int* __restrict__ tgt_ns,
    const int* flag,
    float* __restrict__ row_gt, float* __restrict__ row_cnt,
    float* __restrict__ col_gt, float* __restrict__ col_cnt)
{
    if (*flag == 0) return;
    const int b = blockIdx.y;
    const int src = src_ns[b];
    const int band = blockIdx.x;
    if (band * ROWS >= src) return;
    const int tgt = tgt_ns[b];
    const int wave = threadIdx.x >> 6, lane = threadIdx.x & 63;
    const int base = b * (N_ * M_);

    float4 acg[8], accn[8];
#pragma unroll
    for (int j = 0; j < 8; ++j) { acg[j] = make_float4(0,0,0,0); accn[j] = make_float4(0,0,0,0); }

    const int row0 = band * ROWS + wave * WROWS;
    for (int r = 0; r < WROWS; ++r) {
        const int n = row0 + r;
        if (n >= src) break;
        const float4* prow = (const float4*)(pred + base + n * M_);
        const float4* grow = (const float4*)(gt + base + n * M_);
        float rg = 0.f, rc = 0.f;
#pragma unroll
        for (int j = 0; j < 8; ++j) {
            const int m4 = j * 64 + lane;
            const float4 p4 = prow[m4];
            const float4 g4 = grow[m4];
            const int mb = m4 * 4;
#define P1C(KK, MB) do { \
    const bool ok = (mb + KK) < tgt; \
    float p = fminf(fmaxf(p4.MB, 0.f), 1.f); p = ok ? p : 0.f; \
    const float g = ok ? g4.MB : 0.f; \
    const float gp = p * g; \
    rg += gp; rc += g; \
    acg[j].MB += gp; accn[j].MB += g; \
} while (0)
            P1C(0, x); P1C(1, y); P1C(2, z); P1C(3, w);
#undef P1C
        }
        rg = wave_sum(rg); rc = wave_sum(rc);
        if (lane == 0) { row_gt[b * N_ + n] = rg; row_cnt[b * N_ + n] = rc; }
    }

    __shared__ float4 s_cg[M_ / 4];
    __shared__ float4 s_cc[M_ / 4];
    for (int i = threadIdx.x; i < M_ / 4; i += 256) {
        s_cg[i] = make_float4(0,0,0,0);
        s_cc[i] = make_float4(0,0,0,0);
    }
    __syncthreads();
    for (int w = 0; w < 4; ++w) {
        if (wave == w) {
#pragma unroll
            for (int j = 0; j < 8; ++j) {
                const int i = j * 64 + lane;
                float4 v = s_cg[i];
                v.x += acg[j].x; v.y += acg[j].y; v.z += acg[j].z; v.w += acg[j].w;
                s_cg[i] = v;
                float4 u = s_cc[i];
                u.x += accn[j].x; u.y += accn[j].y; u.z += accn[j].z; u.w += accn[j].w;
                s_cc[i] = u;
            }
        }
        __syncthreads();
    }
    const float* fcg = (const float*)s_cg;
    const float* fcc = (const float*)s_cc;
    for (int i = threadIdx.x; i < M_; i += 256) {
        atomicAdd(&col_gt[b * M_ + i], fcg[i]);
        atomicAdd(&col_cnt[b * M_ + i], fcc[i]);
    }
}

// K3: stream pred ONLY (sparse path). rth known up-front -> single pass for
// src_neg/src_pos/tgt_neg, with exact sparse-g corrections. Dense fallback
// branch reads gt as well.
extern "C" __global__ __launch_bounds__(256) void k_pred(
    const float* __restrict__ pred, const float* __restrict__ gt,
    const int* __restrict__ src_ns, const int* __restrict__ tgt_ns,
    const float* __restrict__ beta_p,
    const float* __restrict__ row_gt, const float* __restrict__ row_cnt,
    const float* __restrict__ col_gt, const float* __restrict__ col_cnt,
    const int* __restrict__ nnz, const int* __restrict__ ent_col,
    const float* __restrict__ ent_val, const int* flag,
    float* __restrict__ src_neg, float* __restrict__ src_pos,
    float* __restrict__ tgt_neg)
{
    const int b = blockIdx.y;
    const int src = src_ns[b];
    const int band = blockIdx.x;
    if (band * ROWS >= src) return;
    const int tgt = tgt_ns[b];
    const float beta = beta_p[0];
    const int wave = threadIdx.x >> 6, lane = threadIdx.x & 63;
    const int base = b * (N_ * M_);
    const bool dense = (*flag != 0);
    const int jmax = (tgt + 255) >> 8;   // wave-uniform tail skip

    // cgb = col_gt - beta (threshold pre-subtracted), cc = col_cnt
    float4 cgb[8], cc[8], tn[8];
    const float4* cg4 = (const float4*)(col_gt + b * M_);
    const float4* cc4 = (const float4*)(col_cnt + b * M_);
#pragma unroll
    for (int j = 0; j < 8; ++j) {
        float4 v = cg4[j * 64 + lane];
        v.x -= beta; v.y -= beta; v.z -= beta; v.w -= beta;
        cgb[j] = v;
        cc[j] = cc4[j * 64 + lane];
        tn[j] = make_float4(0,0,0,0);
    }

    const int row0 = band * ROWS + wave * WROWS;
    if (!dense) {
        for (int r = 0; r < WROWS; ++r) {
            const int n = row0 + r;
            if (n >= src) break;
            const int ri = b * N_ + n;
            const float rc = row_cnt[ri];
            const float rth = row_gt[ri] - beta;
            const float4* prow = (const float4*)(pred + base + n * M_);
            float sneg = 0.f, spos = 0.f;
            // FULLY UNROLLED (static tn/cgb/cc indices -> registers, rule #20);
            // jmax tail-skip as a wave-uniform guard per unrolled iteration.
#pragma unroll
            for (int j = 0; j < 8; ++j) {
                if (j < jmax) {
                    const int m4 = j * 64 + lane;
                    const float4 p4 = prow[m4];
                    const int mb = m4 * 4;
#define P2S(KK, MB) do { \
    const bool ok = (mb + KK) < tgt; \
    float p = fminf(fmaxf(p4.MB, 0.f), 1.f); p = ok ? p : 0.f; \
    const float as = (p >= rth) ? rc : 0.f; \
    const float ds = as * p; \
    sneg += ds * ds; \
    const float at = (p >= cgb[j].MB) ? cc[j].MB : 0.f; \
    const float d = at * p; \
    tn[j].MB += d * d; \
} while (0)
                    P2S(0, x); P2S(1, y); P2S(2, z); P2S(3, w);
#undef P2S
                }
            }
            sneg = wave_sum(sneg);
            // spos base is 0 (g==0 everywhere in base pass); corrections add it.
            if (lane == 0) {
                const int nn0 = nnz[ri];
                const int nn = nn0 < KCAP ? nn0 : KCAP;
                for (int s = 0; s < nn; ++s) {
                    const int c = ent_col[ri * KCAP + s];   // c < tgt by capture
                    const float gv = ent_val[ri * KCAP + s];
                    float pv = pred[base + n * M_ + c];
                    pv = fminf(fmaxf(pv, 0.f), 1.f);
                    // src corrections
                    const float as = (pv >= rth) ? rc : 0.f;
                    const float d0 = as * pv;
                    const float d1 = (as - gv) * pv;
                    sneg += d1 * d1 - d0 * d0;
                    const float gp = gv * pv;
                    spos += gp * gp;
                    // tgt correction
                    const float at = (pv >= col_gt[b * M_ + c] - beta) ? col_cnt[b * M_ + c] : 0.f;
                    const float t0 = at * pv;
                    const float t1 = (at - gv) * pv;
                    atomicAdd(&tgt_neg[b * M_ + c], t1 * t1 - t0 * t0);
                }
                src_neg[ri] = sneg; src_pos[ri] = spos;
            }
        }
    } else {
        for (int r = 0; r < WROWS; ++r) {
            const int n = row0 + r;
            if (n >= src) break;
            const int ri = b * N_ + n;
            const float rc = row_cnt[ri];
            const float rth = row_gt[ri] - beta;
            const float4* prow = (const float4*)(pred + base + n * M_);
            const float4* grow = (const float4*)(gt + base + n * M_);
            float sneg = 0.f, spos = 0.f;
#pragma unroll
            for (int j = 0; j < 8; ++j) {
                const int m4 = j * 64 + lane;
                const float4 p4 = prow[m4];
                const float4 g4 = grow[m4];
                const int mb = m4 * 4;
#define P2D(KK, MB) do { \
    const bool ok = (mb + KK) < tgt; \
    float p = fminf(fmaxf(p4.MB, 0.f), 1.f); p = ok ? p : 0.f; \
    const float gv = ok ? g4.MB : 0.f; \
    const float as = (p >= rth) ? rc : 0.f; \
    const float ds = (as - gv) * p; \
    sneg += ds * ds; \
    const float gp = gv * p; spos += gp * gp; \
    const float at = (p >= cgb[j].MB) ? cc[j].MB : 0.f; \
    const float dt = (at - gv) * p; \
    tn[j].MB += dt * dt; \
} while (0)
                P2D(0, x); P2D(1, y); P2D(2, z); P2D(3, w);
#undef P2D
            }
            sneg = wave_sum(sneg); spos = wave_sum(spos);
            if (lane == 0) { src_neg[ri] = sneg; src_pos[ri] = spos; }
        }
    }

    __shared__ float4 s_tn[M_ / 4];
    for (int i = threadIdx.x; i < M_ / 4; i += 256) s_tn[i] = make_float4(0,0,0,0);
    __syncthreads();
    for (int w = 0; w < 4; ++w) {
        if (wave == w) {
#pragma unroll
            for (int j = 0; j < 8; ++j) {
                const int i = j * 64 + lane;
                float4 v = s_tn[i];
                v.x += tn[j].x; v.y += tn[j].y; v.z += tn[j].z; v.w += tn[j].w;
                s_tn[i] = v;
            }
        }
        __syncthreads();
    }
    const float* ftn = (const float*)s_tn;
    for (int i = threadIdx.x; i < M_; i += 256)
        atomicAdd(&tgt_neg[b * M_ + i], ftn[i]);
}

// Final: corr[b] = dot(tgt_neg, col_cnt), then loss reduction -> single scalar
extern "C" __global__ __launch_bounds__(256) void k_final(
    const float* __restrict__ src_neg, const float* __restrict__ src_pos,
    const float* __restrict__ tgt_neg, const float* __restrict__ col_cnt,
    const int* __restrict__ src_ns, float* __restrict__ out)
{
    const int b = blockIdx.x;
    const int wave = threadIdx.x >> 6, lane = threadIdx.x & 63;
    __shared__ float sredc[4];
    __shared__ float sredl[4];

    float c = 0.f;
    for (int i = threadIdx.x; i < M_; i += 256)
        c += tgt_neg[b * M_ + i] * col_cnt[b * M_ + i];
    c = wave_sum(c);
    if (lane == 0) sredc[wave] = c;
    __syncthreads();
    const float corr = sredc[0] + sredc[1] + sredc[2] + sredc[3];

    const int src = src_ns[b];
    float ls = 0.f;
    for (int n = threadIdx.x; n < src; n += 256) {
        const float sp = src_pos[b * N_ + n];
        const float sn = src_neg[b * N_ + n];
        ls += logf(sp) - logf(1.f + sn + corr);
    }
    ls = wave_sum(ls);
    if (lane == 0) sredl[wave] = ls;
    __syncthreads();
    if (threadIdx.x == 0) {
        const float total = sredl[0] + sredl[1] + sredl[2] + sredl[3];
        float nsum = 0.f;
        for (int i = 0; i < B_; ++i) nsum += (float)src_ns[i];
        atomicAdd(out, -0.5f * total / nsum);
    }
}

extern "C" void kernel_launch(void* const* d_in, const int* in_sizes, int n_in,
                              void* d_out, int out_size, void* d_ws, size_t ws_size,
                              hipStream_t stream)
{
    const float* pred   = (const float*)d_in[0];
    const float* gtp    = (const float*)d_in[1];
    const int*   src_ns = (const int*)d_in[2];
    const int*   tgt_ns = (const int*)d_in[3];
    const float* beta   = (const float*)d_in[4];
    float* out = (float*)d_out;
    float* ws  = (float*)d_ws;

    // zeroed region first: [col_gt][col_cnt][tgt_neg][nnz][flag]
    float* col_gt  = ws;
    float* col_cnt = col_gt  + B_ * M_;
    float* tgt_neg = col_cnt + B_ * M_;
    int*   nnz     = (int*)(tgt_neg + B_ * M_);
    int*   flag    = nnz + B_ * N_;
    float* row_gt  = (float*)(flag + 1);
    float* row_cnt = row_gt  + B_ * N_;
    float* src_neg = row_cnt + B_ * N_;
    float* src_pos = src_neg + B_ * N_;
    int*   ent_col = (int*)(src_pos + B_ * N_);
    float* ent_val = (float*)(ent_col + B_ * N_ * KCAP);

    const size_t zero_bytes = (size_t)(3 * B_ * M_ + B_ * N_ + 1) * sizeof(float);
    hipMemsetAsync(d_ws, 0, zero_bytes, stream);
    hipMemsetAsync(d_out, 0, sizeof(float), stream);

    dim3 grid(N_ / ROWS, B_);
    k_gt<<<grid, 256, 0, stream>>>(gtp, src_ns, tgt_ns, nnz, ent_col, ent_val, flag);
    k_mid<<<(B_ * N_) / 256, 256, 0, stream>>>(pred, src_ns, nnz, ent_col, ent_val, flag,
                                               row_gt, row_cnt, col_gt, col_cnt);
    k_p1d<<<grid, 256, 0, stream>>>(pred, gtp, src_ns, tgt_ns, flag,
                                    row_gt, row_cnt, col_gt, col_cnt);
    k_pred<<<grid, 256, 0, stream>>>(pred, gtp, src_ns, tgt_ns, beta,
                                     row_gt, row_cnt, col_gt, col_cnt,
                                     nnz, ent_col, ent_val, flag,
                                     src_neg, src_pos, tgt_neg);
    k_final<<<B_, 256, 0, stream>>>(src_neg, src_pos, tgt_neg, col_cnt, src_ns, out);
}

// Round 5
// 517.960 us; speedup vs baseline: 1.4628x; 1.1220x over previous
//
#include <hip/hip_runtime.h>

#define B_ 16
#define N_ 2048
#define M_ 2048
#define RROWS 16   // rows per block (band) for split kernels
#define WROWS 4    // rows per wave (4 waves/block)
#define CHUNK 1024 // columns per block
#define NCHUNK (M_ / CHUNK)
#define JCH (CHUNK / 256)  // float4-groups per chunk per lane = 4
#define DROWS 32   // dense-fallback band size
#define DWROWS 8
#define KCAP 4     // sparse-capture capacity per row (overflow -> dense fallback)

__device__ __forceinline__ float wave_sum(float v) {
#pragma unroll
    for (int off = 32; off >= 1; off >>= 1) v += __shfl_xor(v, off);
    return v;
}

// K1: stream gt ONLY; capture nonzero (col,val) per valid row. 16x1024 per block.
extern "C" __global__ __launch_bounds__(256) void k_gt(
    const float* __restrict__ gt,
    const int* __restrict__ src_ns, const int* __restrict__ tgt_ns,
    int* __restrict__ nnz, int* __restrict__ ent_col,
    float* __restrict__ ent_val, int* flag)
{
    const int b = blockIdx.y;
    const int src = src_ns[b];
    const int band = blockIdx.x;
    if (band * RROWS >= src) return;
    const int tgt = tgt_ns[b];
    const int c0 = blockIdx.z * CHUNK;
    const int lim = tgt - c0;              // valid cols in this chunk
    if (lim <= 0) return;
    const int jmaxL = lim >= CHUNK ? JCH : ((lim + 255) >> 8);
    const int wave = threadIdx.x >> 6, lane = threadIdx.x & 63;
    const int bc = b * (N_ * M_) + c0;

    const int row0 = band * RROWS + wave * WROWS;
    for (int r = 0; r < WROWS; ++r) {
        const int n = row0 + r;
        if (n >= src) break;               // rows ascending; wave-uniform
        const int ri = b * N_ + n;
        const float4* grow = (const float4*)(gt + bc + n * M_);
        for (int j = 0; j < jmaxL; ++j) {  // no reg arrays indexed by j: safe dynamic bound
            const int m4 = j * 64 + lane;
            const float4 g4 = grow[m4];
            if (g4.x != 0.f || g4.y != 0.f || g4.z != 0.f || g4.w != 0.f) {
                const int mb = c0 + m4 * 4;
#define GC(KK, MB) do { \
    const int c = mb + KK; \
    const float gv = g4.MB; \
    if (gv != 0.f && c < tgt) { \
        const int slot = atomicAdd(&nnz[ri], 1); \
        if (slot < KCAP) { ent_col[ri * KCAP + slot] = c; ent_val[ri * KCAP + slot] = gv; } \
        else *flag = 1; \
    } \
} while (0)
                GC(0, x); GC(1, y); GC(2, z); GC(3, w);
#undef GC
            }
        }
    }
}

// K2 (tiny): build row_gt/row_cnt/col_gt/col_cnt from captured entries.
extern "C" __global__ __launch_bounds__(256) void k_mid(
    const float* __restrict__ pred,
    const int* __restrict__ src_ns,
    const int* __restrict__ nnz, const int* __restrict__ ent_col,
    const float* __restrict__ ent_val, const int* flag,
    float* __restrict__ row_gt, float* __restrict__ row_cnt,
    float* __restrict__ col_gt, float* __restrict__ col_cnt)
{
    if (*flag) return;   // dense fallback kernel will produce the stats
    const int ri = blockIdx.x * 256 + threadIdx.x;
    const int b = ri >> 11, n = ri & (N_ - 1);
    if (n >= src_ns[b]) { row_gt[ri] = 0.f; row_cnt[ri] = 0.f; return; }
    const int nn0 = nnz[ri];
    const int nn = nn0 < KCAP ? nn0 : KCAP;
    float rg = 0.f, rc = 0.f;
    for (int s = 0; s < nn; ++s) {
        const int c = ent_col[ri * KCAP + s];
        const float gv = ent_val[ri * KCAP + s];
        float p = pred[b * (N_ * M_) + n * M_ + c];
        p = fminf(fmaxf(p, 0.f), 1.f);
        rg += gv * p; rc += gv;
        atomicAdd(&col_gt[b * M_ + c], gv * p);
        atomicAdd(&col_cnt[b * M_ + c], gv);
    }
    row_gt[ri] = rg; row_cnt[ri] = rc;
}

// Dense fallback pass1 (runs only if capture overflowed).
extern "C" __global__ __launch_bounds__(256) void k_p1d(
    const float* __restrict__ pred, const float* __restrict__ gt,
    const int* __restrict__ src_ns, const int* __restrict__ tgt_ns,
    const int* flag,
    float* __restrict__ row_gt, float* __restrict__ row_cnt,
    float* __restrict__ col_gt, float* __restrict__ col_cnt)
{
    if (*flag == 0) return;
    const int b = blockIdx.y;
    const int src = src_ns[b];
    const int band = blockIdx.x;
    if (band * DROWS >= src) return;
    const int tgt = tgt_ns[b];
    const int wave = threadIdx.x >> 6, lane = threadIdx.x & 63;
    const int base = b * (N_ * M_);

    float4 acg[8], accn[8];
#pragma unroll
    for (int j = 0; j < 8; ++j) { acg[j] = make_float4(0,0,0,0); accn[j] = make_float4(0,0,0,0); }

    const int row0 = band * DROWS + wave * DWROWS;
    for (int r = 0; r < DWROWS; ++r) {
        const int n = row0 + r;
        if (n >= src) break;
        const float4* prow = (const float4*)(pred + base + n * M_);
        const float4* grow = (const float4*)(gt + base + n * M_);
        float rg = 0.f, rc = 0.f;
#pragma unroll
        for (int j = 0; j < 8; ++j) {
            const int m4 = j * 64 + lane;
            const float4 p4 = prow[m4];
            const float4 g4 = grow[m4];
            const int mb = m4 * 4;
#define P1C(KK, MB) do { \
    const bool ok = (mb + KK) < tgt; \
    float p = fminf(fmaxf(p4.MB, 0.f), 1.f); p = ok ? p : 0.f; \
    const float g = ok ? g4.MB : 0.f; \
    const float gp = p * g; \
    rg += gp; rc += g; \
    acg[j].MB += gp; accn[j].MB += g; \
} while (0)
            P1C(0, x); P1C(1, y); P1C(2, z); P1C(3, w);
#undef P1C
        }
        rg = wave_sum(rg); rc = wave_sum(rc);
        if (lane == 0) { row_gt[b * N_ + n] = rg; row_cnt[b * N_ + n] = rc; }
    }

    __shared__ float4 s_cg[M_ / 4];
    __shared__ float4 s_cc[M_ / 4];
    for (int i = threadIdx.x; i < M_ / 4; i += 256) {
        s_cg[i] = make_float4(0,0,0,0);
        s_cc[i] = make_float4(0,0,0,0);
    }
    __syncthreads();
    for (int w = 0; w < 4; ++w) {
        if (wave == w) {
#pragma unroll
            for (int j = 0; j < 8; ++j) {
                const int i = j * 64 + lane;
                float4 v = s_cg[i];
                v.x += acg[j].x; v.y += acg[j].y; v.z += acg[j].z; v.w += acg[j].w;
                s_cg[i] = v;
                float4 u = s_cc[i];
                u.x += accn[j].x; u.y += accn[j].y; u.z += accn[j].z; u.w += accn[j].w;
                s_cc[i] = u;
            }
        }
        __syncthreads();
    }
    const float* fcg = (const float*)s_cg;
    const float* fcc = (const float*)s_cc;
    for (int i = threadIdx.x; i < M_; i += 256) {
        atomicAdd(&col_gt[b * M_ + i], fcg[i]);
        atomicAdd(&col_cnt[b * M_ + i], fcc[i]);
    }
}

// K3: stream pred ONLY (sparse path), 16x1024 per block. Row outputs via
// atomics (cross-chunk); sparse-g corrections done by chunk 0 only.
extern "C" __global__ __launch_bounds__(256) void k_pred(
    const float* __restrict__ pred, const float* __restrict__ gt,
    const int* __restrict__ src_ns, const int* __restrict__ tgt_ns,
    const float* __restrict__ beta_p,
    const float* __restrict__ row_gt, const float* __restrict__ row_cnt,
    const float* __restrict__ col_gt, const float* __restrict__ col_cnt,
    const int* __restrict__ nnz, const int* __restrict__ ent_col,
    const float* __restrict__ ent_val, const int* flag,
    float* __restrict__ src_neg, float* __restrict__ src_pos,
    float* __restrict__ tgt_neg)
{
    const int b = blockIdx.y;
    const int src = src_ns[b];
    const int band = blockIdx.x;
    if (band * RROWS >= src) return;
    const int tgt = tgt_ns[b];
    const int c0 = blockIdx.z * CHUNK;
    const bool chunk0 = (c0 == 0);
    const int lim = tgt - c0;
    if (lim <= 0 && !chunk0) return;   // chunk0 must still emit row outputs
    const int jmaxL = lim >= CHUNK ? JCH : (lim > 0 ? ((lim + 255) >> 8) : 0);
    const float beta = beta_p[0];
    const int wave = threadIdx.x >> 6, lane = threadIdx.x & 63;
    const int bfull = b * (N_ * M_);
    const int bc = bfull + c0;
    const bool dense = (*flag != 0);

    // cgb = col_gt - beta (threshold pre-subtracted), cc = col_cnt
    float4 cgb[JCH], cc[JCH], tn[JCH];
    const float4* cg4 = (const float4*)(col_gt + b * M_ + c0);
    const float4* cc4 = (const float4*)(col_cnt + b * M_ + c0);
#pragma unroll
    for (int j = 0; j < JCH; ++j) {
        float4 v = cg4[j * 64 + lane];
        v.x -= beta; v.y -= beta; v.z -= beta; v.w -= beta;
        cgb[j] = v;
        cc[j] = cc4[j * 64 + lane];
        tn[j] = make_float4(0,0,0,0);
    }

    const int row0 = band * RROWS + wave * WROWS;
    if (!dense) {
        for (int r = 0; r < WROWS; ++r) {
            const int n = row0 + r;
            if (n >= src) break;
            const int ri = b * N_ + n;
            const float rc = row_cnt[ri];
            const float rth = row_gt[ri] - beta;
            const float4* prow = (const float4*)(pred + bc + n * M_);
            float sneg = 0.f;
            // fully unrolled (static reg-array indices, rule #20); wave-uniform tail guard
#pragma unroll
            for (int j = 0; j < JCH; ++j) {
                if (j < jmaxL) {
                    const int m4 = j * 64 + lane;
                    const float4 p4 = prow[m4];
                    const int mb = c0 + m4 * 4;
#define P2S(KK, MB) do { \
    const bool ok = (mb + KK) < tgt; \
    float p = fminf(fmaxf(p4.MB, 0.f), 1.f); p = ok ? p : 0.f; \
    const float as = (p >= rth) ? rc : 0.f; \
    const float ds = as * p; \
    sneg += ds * ds; \
    const float at = (p >= cgb[j].MB) ? cc[j].MB : 0.f; \
    const float d = at * p; \
    tn[j].MB += d * d; \
} while (0)
                    P2S(0, x); P2S(1, y); P2S(2, z); P2S(3, w);
#undef P2S
                }
            }
            sneg = wave_sum(sneg);
            if (lane == 0) {
                if (chunk0) {
                    float spos = 0.f;
                    const int nn0 = nnz[ri];
                    const int nn = nn0 < KCAP ? nn0 : KCAP;
                    for (int s = 0; s < nn; ++s) {
                        const int c = ent_col[ri * KCAP + s];   // c < tgt by capture
                        const float gv = ent_val[ri * KCAP + s];
                        float pv = pred[bfull + n * M_ + c];
                        pv = fminf(fmaxf(pv, 0.f), 1.f);
                        // src corrections
                        const float as = (pv >= rth) ? rc : 0.f;
                        const float d0 = as * pv;
                        const float d1 = (as - gv) * pv;
                        sneg += d1 * d1 - d0 * d0;
                        const float gp = gv * pv;
                        spos += gp * gp;
                        // tgt correction
                        const float at = (pv >= col_gt[b * M_ + c] - beta) ? col_cnt[b * M_ + c] : 0.f;
                        const float t0 = at * pv;
                        const float t1 = (at - gv) * pv;
                        atomicAdd(&tgt_neg[b * M_ + c], t1 * t1 - t0 * t0);
                    }
                    atomicAdd(&src_pos[ri], spos);
                }
                atomicAdd(&src_neg[ri], sneg);
            }
        }
    } else {
        for (int r = 0; r < WROWS; ++r) {
            const int n = row0 + r;
            if (n >= src) break;
            const int ri = b * N_ + n;
            const float rc = row_cnt[ri];
            const float rth = row_gt[ri] - beta;
            const float4* prow = (const float4*)(pred + bc + n * M_);
            const float4* grow = (const float4*)(gt + bc + n * M_);
            float sneg = 0.f, spos = 0.f;
#pragma unroll
            for (int j = 0; j < JCH; ++j) {
                if (j < jmaxL) {
                    const int m4 = j * 64 + lane;
                    const float4 p4 = prow[m4];
                    const float4 g4 = grow[m4];
                    const int mb = c0 + m4 * 4;
#define P2D(KK, MB) do { \
    const bool ok = (mb + KK) < tgt; \
    float p = fminf(fmaxf(p4.MB, 0.f), 1.f); p = ok ? p : 0.f; \
    const float gv = ok ? g4.MB : 0.f; \
    const float as = (p >= rth) ? rc : 0.f; \
    const float ds = (as - gv) * p; \
    sneg += ds * ds; \
    const float gp = gv * p; spos += gp * gp; \
    const float at = (p >= cgb[j].MB) ? cc[j].MB : 0.f; \
    const float dt = (at - gv) * p; \
    tn[j].MB += dt * dt; \
} while (0)
                    P2D(0, x); P2D(1, y); P2D(2, z); P2D(3, w);
#undef P2D
                }
            }
            sneg = wave_sum(sneg); spos = wave_sum(spos);
            if (lane == 0) {
                atomicAdd(&src_neg[ri], sneg);
                atomicAdd(&src_pos[ri], spos);
            }
        }
    }

    __shared__ float4 s_tn[CHUNK / 4];
    for (int i = threadIdx.x; i < CHUNK / 4; i += 256) s_tn[i] = make_float4(0,0,0,0);
    __syncthreads();
    for (int w = 0; w < 4; ++w) {
        if (wave == w) {
#pragma unroll
            for (int j = 0; j < JCH; ++j) {
                const int i = j * 64 + lane;
                float4 v = s_tn[i];
                v.x += tn[j].x; v.y += tn[j].y; v.z += tn[j].z; v.w += tn[j].w;
                s_tn[i] = v;
            }
        }
        __syncthreads();
    }
    const float* ftn = (const float*)s_tn;
    for (int i = threadIdx.x; i < CHUNK; i += 256)
        atomicAdd(&tgt_neg[b * M_ + c0 + i], ftn[i]);
}

// Final: corr[b] = dot(tgt_neg, col_cnt), then loss reduction -> single scalar
extern "C" __global__ __launch_bounds__(256) void k_final(
    const float* __restrict__ src_neg, const float* __restrict__ src_pos,
    const float* __restrict__ tgt_neg, const float* __restrict__ col_cnt,
    const int* __restrict__ src_ns, float* __restrict__ out)
{
    const int b = blockIdx.x;
    const int wave = threadIdx.x >> 6, lane = threadIdx.x & 63;
    __shared__ float sredc[4];
    __shared__ float sredl[4];

    float c = 0.f;
    for (int i = threadIdx.x; i < M_; i += 256)
        c += tgt_neg[b * M_ + i] * col_cnt[b * M_ + i];
    c = wave_sum(c);
    if (lane == 0) sredc[wave] = c;
    __syncthreads();
    const float corr = sredc[0] + sredc[1] + sredc[2] + sredc[3];

    const int src = src_ns[b];
    float ls = 0.f;
    for (int n = threadIdx.x; n < src; n += 256) {
        const float sp = src_pos[b * N_ + n];
        const float sn = src_neg[b * N_ + n];
        ls += logf(sp) - logf(1.f + sn + corr);
    }
    ls = wave_sum(ls);
    if (lane == 0) sredl[wave] = ls;
    __syncthreads();
    if (threadIdx.x == 0) {
        const float total = sredl[0] + sredl[1] + sredl[2] + sredl[3];
        float nsum = 0.f;
        for (int i = 0; i < B_; ++i) nsum += (float)src_ns[i];
        atomicAdd(out, -0.5f * total / nsum);
    }
}

extern "C" void kernel_launch(void* const* d_in, const int* in_sizes, int n_in,
                              void* d_out, int out_size, void* d_ws, size_t ws_size,
                              hipStream_t stream)
{
    const float* pred   = (const float*)d_in[0];
    const float* gtp    = (const float*)d_in[1];
    const int*   src_ns = (const int*)d_in[2];
    const int*   tgt_ns = (const int*)d_in[3];
    const float* beta   = (const float*)d_in[4];
    float* out = (float*)d_out;
    float* ws  = (float*)d_ws;

    // zeroed region first: [col_gt][col_cnt][tgt_neg][src_neg][src_pos][nnz][flag]
    float* col_gt  = ws;
    float* col_cnt = col_gt  + B_ * M_;
    float* tgt_neg = col_cnt + B_ * M_;
    float* src_neg = tgt_neg + B_ * M_;
    float* src_pos = src_neg + B_ * N_;
    int*   nnz     = (int*)(src_pos + B_ * N_);
    int*   flag    = nnz + B_ * N_;
    float* row_gt  = (float*)(flag + 1);
    float* row_cnt = row_gt + B_ * N_;
    int*   ent_col = (int*)(row_cnt + B_ * N_);
    float* ent_val = (float*)(ent_col + B_ * N_ * KCAP);

    const size_t zero_bytes = (size_t)(3 * B_ * M_ + 3 * B_ * N_ + 1) * sizeof(float);
    hipMemsetAsync(d_ws, 0, zero_bytes, stream);
    hipMemsetAsync(d_out, 0, sizeof(float), stream);

    dim3 gsplit(N_ / RROWS, B_, NCHUNK);
    k_gt<<<gsplit, 256, 0, stream>>>(gtp, src_ns, tgt_ns, nnz, ent_col, ent_val, flag);
    k_mid<<<(B_ * N_) / 256, 256, 0, stream>>>(pred, src_ns, nnz, ent_col, ent_val, flag,
                                               row_gt, row_cnt, col_gt, col_cnt);
    k_p1d<<<dim3(N_ / DROWS, B_), 256, 0, stream>>>(pred, gtp, src_ns, tgt_ns, flag,
                                                    row_gt, row_cnt, col_gt, col_cnt);
    k_pred<<<gsplit, 256, 0, stream>>>(pred, gtp, src_ns, tgt_ns, beta,
                                       row_gt, row_cnt, col_gt, col_cnt,
                                       nnz, ent_col, ent_val, flag,
                                       src_neg, src_pos, tgt_neg);
    k_final<<<B_, 256, 0, stream>>>(src_neg, src_pos, tgt_neg, col_cnt, src_ns, out);
}

// Round 6
// 500.037 us; speedup vs baseline: 1.5153x; 1.0358x over previous
//
#include <hip/hip_runtime.h>

#define B_ 16
#define N_ 2048
#define M_ 2048
#define RROWS 16   // rows per block (band) for split kernels
#define WROWS 4    // rows per wave (4 waves/block)
#define CHUNK 1024 // columns per block
#define NCHUNK (M_ / CHUNK)
#define JCH (CHUNK / 256)  // float4-groups per chunk per lane = 4
#define DROWS 32   // dense-fallback band size
#define DWROWS 8
#define KCAP 4     // sparse-capture capacity per row (overflow -> dense fallback)

__device__ __forceinline__ float wave_sum(float v) {
#pragma unroll
    for (int off = 32; off >= 1; off >>= 1) v += __shfl_xor(v, off);
    return v;
}

// K1: stream gt ONLY; capture nonzero (col,val) per valid row. 16x1024 tile.
// Unconditional 4x float4 loads (always in-bounds w.r.t. M_); c<tgt guards validity.
extern "C" __global__ __launch_bounds__(256) void k_gt(
    const float* __restrict__ gt,
    const int* __restrict__ src_ns, const int* __restrict__ tgt_ns,
    int* __restrict__ nnz, int* __restrict__ ent_col,
    float* __restrict__ ent_val, int* flag)
{
    const int b = blockIdx.y;
    const int src = src_ns[b];
    const int band = blockIdx.x;
    if (band * RROWS >= src) return;
    const int tgt = tgt_ns[b];
    const int c0 = blockIdx.z * CHUNK;
    if (tgt - c0 <= 0) return;             // whole chunk past tgt
    const int wave = threadIdx.x >> 6, lane = threadIdx.x & 63;
    const int bc = b * (N_ * M_) + c0;

    const int row0 = band * RROWS + wave * WROWS;
    for (int r = 0; r < WROWS; ++r) {
        const int n = row0 + r;
        if (n >= src) break;               // rows ascending; wave-uniform
        const int ri = b * N_ + n;
        const float4* grow = (const float4*)(gt + bc + n * M_);
        const float4 g0 = grow[lane];
        const float4 g1 = grow[64 + lane];
        const float4 g2 = grow[128 + lane];
        const float4 g3 = grow[192 + lane];
#define GTEST(GV, J) \
        if (GV.x != 0.f || GV.y != 0.f || GV.z != 0.f || GV.w != 0.f) { \
            const int mb = c0 + (J * 64 + lane) * 4; \
            GC(GV, 0, x); GC(GV, 1, y); GC(GV, 2, z); GC(GV, 3, w); \
        }
#define GC(GV, KK, MB) do { \
    const int c = mb + KK; \
    const float gv = GV.MB; \
    if (gv != 0.f && c < tgt) { \
        const int slot = atomicAdd(&nnz[ri], 1); \
        if (slot < KCAP) { ent_col[ri * KCAP + slot] = c; ent_val[ri * KCAP + slot] = gv; } \
        else *flag = 1; \
    } \
} while (0)
        GTEST(g0, 0) GTEST(g1, 1) GTEST(g2, 2) GTEST(g3, 3)
#undef GC
#undef GTEST
    }
}

// K2 (tiny): build row_gt/row_cnt/col_gt/col_cnt from captured entries.
extern "C" __global__ __launch_bounds__(256) void k_mid(
    const float* __restrict__ pred,
    const int* __restrict__ src_ns,
    const int* __restrict__ nnz, const int* __restrict__ ent_col,
    const float* __restrict__ ent_val, const int* flag,
    float* __restrict__ row_gt, float* __restrict__ row_cnt,
    float* __restrict__ col_gt, float* __restrict__ col_cnt)
{
    if (*flag) return;   // dense fallback kernel will produce the stats
    const int ri = blockIdx.x * 256 + threadIdx.x;
    const int b = ri >> 11, n = ri & (N_ - 1);
    if (n >= src_ns[b]) { row_gt[ri] = 0.f; row_cnt[ri] = 0.f; return; }
    const int nn0 = nnz[ri];
    const int nn = nn0 < KCAP ? nn0 : KCAP;
    float rg = 0.f, rc = 0.f;
    for (int s = 0; s < nn; ++s) {
        const int c = ent_col[ri * KCAP + s];
        const float gv = ent_val[ri * KCAP + s];
        float p = pred[b * (N_ * M_) + n * M_ + c];
        p = fminf(fmaxf(p, 0.f), 1.f);
        rg += gv * p; rc += gv;
        atomicAdd(&col_gt[b * M_ + c], gv * p);
        atomicAdd(&col_cnt[b * M_ + c], gv);
    }
    row_gt[ri] = rg; row_cnt[ri] = rc;
}

// Dense fallback pass1 (runs only if capture overflowed).
extern "C" __global__ __launch_bounds__(256) void k_p1d(
    const float* __restrict__ pred, const float* __restrict__ gt,
    const int* __restrict__ src_ns, const int* __restrict__ tgt_ns,
    const int* flag,
    float* __restrict__ row_gt, float* __restrict__ row_cnt,
    float* __restrict__ col_gt, float* __restrict__ col_cnt)
{
    if (*flag == 0) return;
    const int b = blockIdx.y;
    const int src = src_ns[b];
    const int band = blockIdx.x;
    if (band * DROWS >= src) return;
    const int tgt = tgt_ns[b];
    const int wave = threadIdx.x >> 6, lane = threadIdx.x & 63;
    const int base = b * (N_ * M_);

    float4 acg[8], accn[8];
#pragma unroll
    for (int j = 0; j < 8; ++j) { acg[j] = make_float4(0,0,0,0); accn[j] = make_float4(0,0,0,0); }

    const int row0 = band * DROWS + wave * DWROWS;
    for (int r = 0; r < DWROWS; ++r) {
        const int n = row0 + r;
        if (n >= src) break;
        const float4* prow = (const float4*)(pred + base + n * M_);
        const float4* grow = (const float4*)(gt + base + n * M_);
        float rg = 0.f, rc = 0.f;
#pragma unroll
        for (int j = 0; j < 8; ++j) {
            const int m4 = j * 64 + lane;
            const float4 p4 = prow[m4];
            const float4 g4 = grow[m4];
            const int mb = m4 * 4;
#define P1C(KK, MB) do { \
    const bool ok = (mb + KK) < tgt; \
    float p = fminf(fmaxf(p4.MB, 0.f), 1.f); p = ok ? p : 0.f; \
    const float g = ok ? g4.MB : 0.f; \
    const float gp = p * g; \
    rg += gp; rc += g; \
    acg[j].MB += gp; accn[j].MB += g; \
} while (0)
            P1C(0, x); P1C(1, y); P1C(2, z); P1C(3, w);
#undef P1C
        }
        rg = wave_sum(rg); rc = wave_sum(rc);
        if (lane == 0) { row_gt[b * N_ + n] = rg; row_cnt[b * N_ + n] = rc; }
    }

    __shared__ float4 s_cg[M_ / 4];
    __shared__ float4 s_cc[M_ / 4];
    for (int i = threadIdx.x; i < M_ / 4; i += 256) {
        s_cg[i] = make_float4(0,0,0,0);
        s_cc[i] = make_float4(0,0,0,0);
    }
    __syncthreads();
    for (int w = 0; w < 4; ++w) {
        if (wave == w) {
#pragma unroll
            for (int j = 0; j < 8; ++j) {
                const int i = j * 64 + lane;
                float4 v = s_cg[i];
                v.x += acg[j].x; v.y += acg[j].y; v.z += acg[j].z; v.w += acg[j].w;
                s_cg[i] = v;
                float4 u = s_cc[i];
                u.x += accn[j].x; u.y += accn[j].y; u.z += accn[j].z; u.w += accn[j].w;
                s_cc[i] = u;
            }
        }
        __syncthreads();
    }
    const float* fcg = (const float*)s_cg;
    const float* fcc = (const float*)s_cc;
    for (int i = threadIdx.x; i < M_; i += 256) {
        atomicAdd(&col_gt[b * M_ + i], fcg[i]);
        atomicAdd(&col_cnt[b * M_ + i], fcc[i]);
    }
}

// K3: stream pred ONLY (sparse path). tgt_neg is NEVER materialized: each
// block dots its local tn against cc (already in regs) and atomically adds
// ONE scalar per block into corr[b]. Sparse corrections fold in as
// (t1^2-t0^2)*col_cnt[c]. Dense fallback reads gt too, same block-dot.
extern "C" __global__ __launch_bounds__(256) void k_pred(
    const float* __restrict__ pred, const float* __restrict__ gt,
    const int* __restrict__ src_ns, const int* __restrict__ tgt_ns,
    const float* __restrict__ beta_p,
    const float* __restrict__ row_gt, const float* __restrict__ row_cnt,
    const float* __restrict__ col_gt, const float* __restrict__ col_cnt,
    const int* __restrict__ nnz, const int* __restrict__ ent_col,
    const float* __restrict__ ent_val, const int* flag,
    float* __restrict__ src_neg, float* __restrict__ src_pos,
    float* __restrict__ corr)
{
    const int b = blockIdx.y;
    const int src = src_ns[b];
    const int band = blockIdx.x;
    if (band * RROWS >= src) return;
    const int tgt = tgt_ns[b];
    const int c0 = blockIdx.z * CHUNK;
    const bool chunk0 = (c0 == 0);
    if (tgt - c0 <= 0 && !chunk0) return;  // chunk0 must still emit row outputs
    const float beta = beta_p[0];
    const int wave = threadIdx.x >> 6, lane = threadIdx.x & 63;
    const int bfull = b * (N_ * M_);
    const int bc = bfull + c0;
    const bool dense = (*flag != 0);

    // cgb = col_gt - beta (threshold pre-subtracted), cc = col_cnt
    float4 cgb[JCH], cc[JCH], tn[JCH];
    const float4* cg4 = (const float4*)(col_gt + b * M_ + c0);
    const float4* cc4 = (const float4*)(col_cnt + b * M_ + c0);
#pragma unroll
    for (int j = 0; j < JCH; ++j) {
        float4 v = cg4[j * 64 + lane];
        v.x -= beta; v.y -= beta; v.z -= beta; v.w -= beta;
        cgb[j] = v;
        cc[j] = cc4[j * 64 + lane];
        tn[j] = make_float4(0,0,0,0);
    }

    float cadd = 0.f;   // lane0-only: sparse-correction contribution to corr[b]
    const int row0 = band * RROWS + wave * WROWS;
    if (!dense) {
        for (int r = 0; r < WROWS; ++r) {
            const int n = row0 + r;
            if (n >= src) break;
            const int ri = b * N_ + n;
            const float rc = row_cnt[ri];
            const float rth = row_gt[ri] - beta;
            const float4* prow = (const float4*)(pred + bc + n * M_);
            const float4 p0 = prow[lane];
            const float4 p1 = prow[64 + lane];
            const float4 p2 = prow[128 + lane];
            const float4 p3 = prow[192 + lane];
            float sneg = 0.f;
#define P2S(PV, J, KK, MB) do { \
    const bool ok = (c0 + (J * 64 + lane) * 4 + KK) < tgt; \
    float p = fminf(fmaxf(PV.MB, 0.f), 1.f); p = ok ? p : 0.f; \
    const float as = (p >= rth) ? rc : 0.f; \
    const float ds = as * p; \
    sneg += ds * ds; \
    const float at = (p >= cgb[J].MB) ? cc[J].MB : 0.f; \
    const float d = at * p; \
    tn[J].MB += d * d; \
} while (0)
#define P2SV(PV, J) P2S(PV, J, 0, x); P2S(PV, J, 1, y); P2S(PV, J, 2, z); P2S(PV, J, 3, w);
            P2SV(p0, 0) P2SV(p1, 1) P2SV(p2, 2) P2SV(p3, 3)
#undef P2SV
#undef P2S
            sneg = wave_sum(sneg);
            if (lane == 0) {
                if (chunk0) {
                    float spos = 0.f;
                    const int nn0 = nnz[ri];
                    const int nn = nn0 < KCAP ? nn0 : KCAP;
                    for (int s = 0; s < nn; ++s) {
                        const int c = ent_col[ri * KCAP + s];   // c < tgt by capture
                        const float gv = ent_val[ri * KCAP + s];
                        float pv = pred[bfull + n * M_ + c];
                        pv = fminf(fmaxf(pv, 0.f), 1.f);
                        // src corrections
                        const float as = (pv >= rth) ? rc : 0.f;
                        const float d0 = as * pv;
                        const float d1 = (as - gv) * pv;
                        sneg += d1 * d1 - d0 * d0;
                        const float gp = gv * pv;
                        spos += gp * gp;
                        // tgt correction, folded directly into corr[b]
                        const float ccv = col_cnt[b * M_ + c];
                        const float at = (pv >= col_gt[b * M_ + c] - beta) ? ccv : 0.f;
                        const float t0 = at * pv;
                        const float t1 = (at - gv) * pv;
                        cadd += (t1 * t1 - t0 * t0) * ccv;
                    }
                    atomicAdd(&src_pos[ri], spos);
                }
                atomicAdd(&src_neg[ri], sneg);
            }
        }
    } else {
        for (int r = 0; r < WROWS; ++r) {
            const int n = row0 + r;
            if (n >= src) break;
            const int ri = b * N_ + n;
            const float rc = row_cnt[ri];
            const float rth = row_gt[ri] - beta;
            const float4* prow = (const float4*)(pred + bc + n * M_);
            const float4* grow = (const float4*)(gt + bc + n * M_);
            const float4 p0 = prow[lane];
            const float4 p1 = prow[64 + lane];
            const float4 p2 = prow[128 + lane];
            const float4 p3 = prow[192 + lane];
            const float4 g0 = grow[lane];
            const float4 g1 = grow[64 + lane];
            const float4 g2 = grow[128 + lane];
            const float4 g3 = grow[192 + lane];
            float sneg = 0.f, spos = 0.f;
#define P2D(PV, GV, J, KK, MB) do { \
    const bool ok = (c0 + (J * 64 + lane) * 4 + KK) < tgt; \
    float p = fminf(fmaxf(PV.MB, 0.f), 1.f); p = ok ? p : 0.f; \
    const float gv = ok ? GV.MB : 0.f; \
    const float as = (p >= rth) ? rc : 0.f; \
    const float ds = (as - gv) * p; \
    sneg += ds * ds; \
    const float gp = gv * p; spos += gp * gp; \
    const float at = (p >= cgb[J].MB) ? cc[J].MB : 0.f; \
    const float dt = (at - gv) * p; \
    tn[J].MB += dt * dt; \
} while (0)
#define P2DV(PV, GV, J) P2D(PV, GV, J, 0, x); P2D(PV, GV, J, 1, y); P2D(PV, GV, J, 2, z); P2D(PV, GV, J, 3, w);
            P2DV(p0, g0, 0) P2DV(p1, g1, 1) P2DV(p2, g2, 2) P2DV(p3, g3, 3)
#undef P2DV
#undef P2D
            sneg = wave_sum(sneg); spos = wave_sum(spos);
            if (lane == 0) {
                atomicAdd(&src_neg[ri], sneg);
                atomicAdd(&src_pos[ri], spos);
            }
        }
    }

    // block-local dot tn . cc  (+ lane0's cadd)  ->  one atomic into corr[b]
    float dp = cadd;
#pragma unroll
    for (int j = 0; j < JCH; ++j)
        dp += tn[j].x * cc[j].x + tn[j].y * cc[j].y + tn[j].z * cc[j].z + tn[j].w * cc[j].w;
    dp = wave_sum(dp);
    __shared__ float sred[4];
    if (lane == 0) sred[wave] = dp;
    __syncthreads();
    if (threadIdx.x == 0)
        atomicAdd(&corr[b], sred[0] + sred[1] + sred[2] + sred[3]);
}

// Final: loss reduction over rows (corr[b] already accumulated by k_pred).
// 4 blocks per batch for parallelism.
extern "C" __global__ __launch_bounds__(256) void k_final(
    const float* __restrict__ src_neg, const float* __restrict__ src_pos,
    const float* __restrict__ corr_p, const int* __restrict__ src_ns,
    float* __restrict__ out)
{
    const int b = blockIdx.x >> 2;
    const int part = blockIdx.x & 3;
    const int wave = threadIdx.x >> 6, lane = threadIdx.x & 63;
    const int src = src_ns[b];
    const int n0 = part * (N_ / 4);
    const int n1 = n0 + (N_ / 4);
    const float corr = corr_p[b];

    float ls = 0.f;
    for (int n = n0 + threadIdx.x; n < n1 && n < src; n += 256) {
        const float sp = src_pos[b * N_ + n];
        const float sn = src_neg[b * N_ + n];
        ls += logf(sp) - logf(1.f + sn + corr);
    }
    ls = wave_sum(ls);
    __shared__ float sredl[4];
    if (lane == 0) sredl[wave] = ls;
    __syncthreads();
    if (threadIdx.x == 0) {
        const float total = sredl[0] + sredl[1] + sredl[2] + sredl[3];
        float nsum = 0.f;
        for (int i = 0; i < B_; ++i) nsum += (float)src_ns[i];
        atomicAdd(out, -0.5f * total / nsum);
    }
}

extern "C" void kernel_launch(void* const* d_in, const int* in_sizes, int n_in,
                              void* d_out, int out_size, void* d_ws, size_t ws_size,
                              hipStream_t stream)
{
    const float* pred   = (const float*)d_in[0];
    const float* gtp    = (const float*)d_in[1];
    const int*   src_ns = (const int*)d_in[2];
    const int*   tgt_ns = (const int*)d_in[3];
    const float* beta   = (const float*)d_in[4];
    float* out = (float*)d_out;
    float* ws  = (float*)d_ws;

    // zeroed region first: [col_gt][col_cnt][src_neg][src_pos][corr][nnz][flag]
    float* col_gt  = ws;
    float* col_cnt = col_gt  + B_ * M_;
    float* src_neg = col_cnt + B_ * M_;
    float* src_pos = src_neg + B_ * N_;
    float* corr    = src_pos + B_ * N_;
    int*   nnz     = (int*)(corr + B_);
    int*   flag    = nnz + B_ * N_;
    float* row_gt  = (float*)(flag + 1);
    float* row_cnt = row_gt + B_ * N_;
    int*   ent_col = (int*)(row_cnt + B_ * N_);
    float* ent_val = (float*)(ent_col + B_ * N_ * KCAP);

    const size_t zero_bytes = (size_t)(2 * B_ * M_ + 3 * B_ * N_ + B_ + 1) * sizeof(float);
    hipMemsetAsync(d_ws, 0, zero_bytes, stream);
    hipMemsetAsync(d_out, 0, sizeof(float), stream);

    dim3 gsplit(N_ / RROWS, B_, NCHUNK);
    k_gt<<<gsplit, 256, 0, stream>>>(gtp, src_ns, tgt_ns, nnz, ent_col, ent_val, flag);
    k_mid<<<(B_ * N_) / 256, 256, 0, stream>>>(pred, src_ns, nnz, ent_col, ent_val, flag,
                                               row_gt, row_cnt, col_gt, col_cnt);
    k_p1d<<<dim3(N_ / DROWS, B_), 256, 0, stream>>>(pred, gtp, src_ns, tgt_ns, flag,
                                                    row_gt, row_cnt, col_gt, col_cnt);
    k_pred<<<gsplit, 256, 0, stream>>>(pred, gtp, src_ns, tgt_ns, beta,
                                       row_gt, row_cnt, col_gt, col_cnt,
                                       nnz, ent_col, ent_val, flag,
                                       src_neg, src_pos, corr);
    k_final<<<B_ * 4, 256, 0, stream>>>(src_neg, src_pos, corr, src_ns, out);
}